// Round 15
// baseline (890.569 us; speedup 1.0000x reference)
//
#include <hip/hip_runtime.h>
#include <hip/hip_bf16.h>

// AttnDecoderRNN on MI355X.
// R8/R9: gates GEMM fused into LSTM, 63 slices x 4 WGs (280 us/layer).
// R10-R13: slice-count / LDS-weights / reg-residency / XCD-swizzles all
//          neutral or regressed — LSTM topology is saturated at ~280.
// R14: (a) embedding fused into LSTM-1 (emb is 64KB = L2-resident;
//      per-step gather replaces the 52MB X HBM stream; embed_k removed).
//      (b) bias_sum folded into lstm init (2 launches removed).
//      (c) attn/gemm_mlp1 reverted to R8 measured-best 2D-grid forms.

#define B_    1000
#define T_    101
#define E_    256
#define H_    256
#define NG    1024      // 4H
#define NSLICE 63

typedef __bf16 bf16;
typedef __bf16 bf16x8 __attribute__((ext_vector_type(8)));
typedef float  f32x4  __attribute__((ext_vector_type(4)));

__device__ __forceinline__ bf16 f2b(float f){
  unsigned u = __builtin_bit_cast(unsigned, f);
  u += 0x7FFFu + ((u >> 16) & 1u);               // RNE
  unsigned short h = (unsigned short)(u >> 16);
  return __builtin_bit_cast(bf16, h);
}
__device__ __forceinline__ unsigned packbf(float a, float b){
  unsigned ua = __builtin_bit_cast(unsigned, a);
  ua += 0x7FFFu + ((ua >> 16) & 1u);
  unsigned ub = __builtin_bit_cast(unsigned, b);
  ub += 0x7FFFu + ((ub >> 16) & 1u);
  return (ua >> 16) | (ub & 0xffff0000u);
}
__device__ __forceinline__ float sigm(float x){ return 1.f/(1.f + __expf(-x)); }
__device__ __forceinline__ float tanh_(float x){ return 2.f/(1.f + __expf(-2.f*x)) - 1.f; }

// ---- pack W[N][K] f32 -> Bp[K/32][N][32] bf16 (MFMA B-fragment order) ----
__global__ void pack_bT(const float* __restrict__ src, bf16* __restrict__ dst,
                        int N, int K)
{
  const long batch = blockIdx.y;
  src += batch * (long)N * K;
  dst += batch * (long)(K/32) * N * 32;
  const int tid = blockIdx.x * blockDim.x + threadIdx.x;
  const int total = (K/32) * N * 4;
  if (tid >= total) return;
  const int kkc = tid & 3;
  const int rem = tid >> 2;
  const int n = rem % N;
  const int q = rem / N;
  const float* s = src + (long)n*K + q*32 + kkc*8;
  bf16x8 v;
  #pragma unroll
  for (int e=0;e<8;e++) v[e] = f2b(s[e]);
  *reinterpret_cast<bf16x8*>(dst + ((long)q*N + n)*32 + kkc*8) = v;
}

// ---- f32 transpose: dst[k][j] = src[j][k], src is [N][K] ----
__global__ void tr_f32(const float* __restrict__ src, float* __restrict__ dst,
                       int N, int K)
{
  const int id = blockIdx.x * blockDim.x + threadIdx.x;
  if (id >= N*K) return;
  const int k = id / N, j = id % N;
  dst[(long)k*N + j] = src[(long)j*K + k];
}

// ---- fused LSTM: 63 slices x 4 WGs; optional embedded-x gather ----
#define MF(a,b,c) __builtin_amdgcn_mfma_f32_16x16x32_bf16((a),(b),(c),0,0,0)
#define LDW(q_,off_)  (*reinterpret_cast<const bf16x8*>(bbW + ((long)(q_)*NG + (off_))*32))
#define LDX8(q_,off_) (*reinterpret_cast<const bf16x8*>(bbX + ((long)(q_)*NG + (off_))*32))

#define XK_ALL() { \
  bf16x8 xA0 = LDX8(0,0), xA1 = LDX8(0,16), xB0, xB1; \
  _Pragma("unroll") \
  for (int h2x=0; h2x<4; ++h2x){ \
    const int q0x = 2*h2x; \
    xB0 = LDX8(q0x+1,0); xB1 = LDX8(q0x+1,16); \
    { bf16x8 ax = *reinterpret_cast<const bf16x8*>(&xbuf[l16*264 + q0x*32 + lg*8]); \
      acc0 = MF(ax,xA0,acc0); acc1 = MF(ax,xA1,acc1); } \
    if (q0x+2 < 8){ xA0 = LDX8(q0x+2,0); xA1 = LDX8(q0x+2,16); } \
    { bf16x8 ax = *reinterpret_cast<const bf16x8*>(&xbuf[l16*264 + (q0x+1)*32 + lg*8]); \
      acc0 = MF(ax,xB0,acc0); acc1 = MF(ax,xB1,acc1); } \
  } }

__launch_bounds__(512, 1)
__global__ void lstm_v6(const bf16* __restrict__ X, const int* __restrict__ ids,
                        const float* __restrict__ emb,
                        const bf16* __restrict__ Wihp, const bf16* __restrict__ Whhp,
                        const float* __restrict__ bih, const float* __restrict__ bhh,
                        bf16* __restrict__ Hout, unsigned* __restrict__ hX,
                        unsigned* __restrict__ flags, const int gather)
{
  __shared__ __align__(16) bf16 hbuf[16*264];   // h_{t-1}/h_t (16 x 256, padded)
  __shared__ __align__(16) bf16 xbuf[16*264];   // x_t / x_{t+1}
  __shared__ float gstage[256*17];               // gate partials [local col][row]
  const int bid = blockIdx.x;
  const int s = bid >> 2, g = bid & 3;
  const int b0 = s * 16;
  const int tid = threadIdx.x;
  const int wave = tid >> 6, lane = tid & 63;
  const int l16 = lane & 15, lg = lane >> 4;
  const int qd  = wave >> 1;               // gate quadrant of this wave
  const int h32 = (wave & 1) * 32;         // 32-col half within the 64

  const bf16* bbW = Whhp + ((long)(qd*256 + g*64 + h32 + l16) * 32 + lg*8);
  const bf16* bbX = Wihp + ((long)(qd*256 + g*64 + h32 + l16) * 32 + lg*8);

  const int row = tid >> 5;            // 0..15
  const int k32 = tid & 31;
  const int j2  = k32 * 2;             // [0,64)
  float c0 = 0.f, c1 = 0.f;

  const int  b      = b0 + row;
  const int  bclamp = (b < B_) ? b : (B_-1);
  const long grow   = (long)b * T_;
  const bf16* xp  = X    + grow*256 + k32*8;   // valid only when !gather
  bf16*       hop = Hout + grow*256 + g*64 + j2;

  const float bvi0 = bih[      g*64 + j2    ] + bhh[      g*64 + j2    ];
  const float bvi1 = bih[      g*64 + j2 + 1] + bhh[      g*64 + j2 + 1];
  const float bvf0 = bih[256 + g*64 + j2    ] + bhh[256 + g*64 + j2    ];
  const float bvf1 = bih[256 + g*64 + j2 + 1] + bhh[256 + g*64 + j2 + 1];
  const float bvg0 = bih[512 + g*64 + j2    ] + bhh[512 + g*64 + j2    ];
  const float bvg1 = bih[512 + g*64 + j2 + 1] + bhh[512 + g*64 + j2 + 1];
  const float bvo0 = bih[768 + g*64 + j2    ] + bhh[768 + g*64 + j2    ];
  const float bvo1 = bih[768 + g*64 + j2 + 1] + bhh[768 + g*64 + j2 + 1];

  unsigned* flagw = flags + s*16;       // 4 words per slice, 64B line
  unsigned* hx0 = hX + (size_t)s*2048 + row*128 + g*32 + k32;
  unsigned* hx1 = hx0 + (size_t)NSLICE*2048;
  const unsigned* rb0 = hX + (size_t)s*2048 + row*128;
  const unsigned* rb1 = rb0 + (size_t)NSLICE*2048;

  const int qo0 = 2*g, qo1 = 2*g + 1;    // Whh K-chunks covering own h-cols

  for (int i = tid; i < 16*264; i += 512) hbuf[i] = f2b(0.f);
  {
    bf16x8 x0;
    if (gather){
      const int id = ids[(long)bclamp*T_];
      const float* e = emb + (long)id*E_ + k32*8;
      #pragma unroll
      for (int j=0;j<8;j++) x0[j] = f2b(e[j]);
    } else {
      x0 = *reinterpret_cast<const bf16x8*>(xp);
    }
    *reinterpret_cast<bf16x8*>(&xbuf[row*264 + k32*8]) = x0;   // x_0
  }
  __syncthreads();

  bf16x8 f0[6], f1[6];                   // remK weights (wait-window refresh)
  #pragma unroll
  for (int i=0;i<6;++i){
    const int qn = (qo0 + 2 + i) & 7;
    f0[i] = LDW(qn, 0);
    f1[i] = LDW(qn, 16);
  }

  // prologue: acc = x-K(x_0); h_{-1}=0 so h-K contributes nothing
  f32x4 acc0 = {0.f,0.f,0.f,0.f}, acc1 = {0.f,0.f,0.f,0.f};
  XK_ALL();

  for (int t = 0; t < T_; ++t){
    // x_{t+1} fetch (L2-resident gather or bf16 stream)
    bf16x8 xreg;
    {
      const int tt = (t < T_-1) ? t+1 : T_-1;
      if (gather){
        const int id = ids[(long)bclamp*T_ + tt];
        const float* e = emb + (long)id*E_ + k32*8;
        #pragma unroll
        for (int j=0;j<8;j++) xreg[j] = f2b(e[j]);
      } else {
        xreg = *reinterpret_cast<const bf16x8*>(xp + (long)tt*256);
      }
    }

    // --- remK: 6 Whh chunks over sibling h-cols ---
    #pragma unroll
    for (int i = 0; i < 6; ++i){
      const int qi = (qo0 + 2 + i) & 7;
      bf16x8 a = *reinterpret_cast<const bf16x8*>(&hbuf[l16*264 + qi*32 + lg*8]);
      acc0 = MF(a, f0[i], acc0);
      acc1 = MF(a, f1[i], acc1);
    }
    // dump gate partials, transposed [local col][17]
    {
      const int jj = wave*32 + l16;
      float* gc0 = &gstage[jj*17 + lg*4];
      gc0[0]=acc0[0]; gc0[1]=acc0[1]; gc0[2]=acc0[2]; gc0[3]=acc0[3];
      float* gc1 = &gstage[(jj+16)*17 + lg*4];
      gc1[0]=acc1[0]; gc1[1]=acc1[1]; gc1[2]=acc1[2]; gc1[3]=acc1[3];
    }
    __syncthreads();   // B1: gstage visible; hbuf/xbuf reads done

    // --- elementwise: 2 h-cols per thread ---
    const float i0 = sigm (bvi0 + gstage[(j2      )*17 + row]);
    const float i1 = sigm (bvi1 + gstage[(j2 +   1)*17 + row]);
    const float f0e= sigm (bvf0 + gstage[(j2 +  64)*17 + row]);
    const float f1e= sigm (bvf1 + gstage[(j2 +  65)*17 + row]);
    const float g0e= tanh_(bvg0 + gstage[(j2 + 128)*17 + row]);
    const float g1e= tanh_(bvg1 + gstage[(j2 + 129)*17 + row]);
    const float o0 = sigm (bvo0 + gstage[(j2 + 192)*17 + row]);
    const float o1 = sigm (bvo1 + gstage[(j2 + 193)*17 + row]);
    c0 = f0e*c0 + i0*g0e;
    c1 = f1e*c1 + i1*g1e;
    const unsigned hw = packbf(o0*tanh_(c0), o1*tanh_(c1));

    // own h -> hbuf; x_{t+1} -> xbuf; publish h -> LLC (pre-flag drain)
    *reinterpret_cast<unsigned*>(&hbuf[row*264 + g*64 + j2]) = hw;
    *reinterpret_cast<bf16x8*>(&xbuf[row*264 + k32*8]) = xreg;
    __hip_atomic_store((t&1) ? hx1 : hx0, hw, __ATOMIC_RELAXED, __HIP_MEMORY_SCOPE_AGENT);

    __syncthreads();   // B2: drains hX publish
    if (tid == 0)
      __hip_atomic_store(flagw + g, (unsigned)(t+1),
                         __ATOMIC_RELAXED, __HIP_MEMORY_SCOPE_AGENT);

    // Hout store off the pre-flag drain path
    *reinterpret_cast<unsigned*>(hop + (long)t*256) = hw;

    // --- wait window: own-K(h_t) + x-K(x_{t+1}) + remK weight refresh ---
    {
      bf16x8 o00 = LDW(qo0, 0), o01 = LDW(qo0, 16);
      bf16x8 o10 = LDW(qo1, 0), o11 = LDW(qo1, 16);
      acc0 = f32x4{0.f,0.f,0.f,0.f};
      acc1 = f32x4{0.f,0.f,0.f,0.f};
      bf16x8 a0 = *reinterpret_cast<const bf16x8*>(&hbuf[l16*264 + qo0*32 + lg*8]);
      acc0 = MF(a0, o00, acc0); acc1 = MF(a0, o01, acc1);
      bf16x8 a1 = *reinterpret_cast<const bf16x8*>(&hbuf[l16*264 + qo1*32 + lg*8]);
      acc0 = MF(a1, o10, acc0); acc1 = MF(a1, o11, acc1);
      XK_ALL();
      #pragma unroll
      for (int i=0;i<6;++i){
        const int qn = (qo0 + 2 + i) & 7;
        f0[i] = LDW(qn, 0);
        f1[i] = LDW(qn, 16);
      }
    }

    // --- wait all 4 WGs (poll 4 per-WG words), pull siblings' h-blocks ---
    {
      const unsigned tgt = (unsigned)(t+1);
      if (lane == 0){
        int guard = 0;
        for (;;){
          const unsigned a0 = __hip_atomic_load(flagw+0, __ATOMIC_RELAXED, __HIP_MEMORY_SCOPE_AGENT);
          const unsigned a1 = __hip_atomic_load(flagw+1, __ATOMIC_RELAXED, __HIP_MEMORY_SCOPE_AGENT);
          const unsigned a2 = __hip_atomic_load(flagw+2, __ATOMIC_RELAXED, __HIP_MEMORY_SCOPE_AGENT);
          const unsigned a3 = __hip_atomic_load(flagw+3, __ATOMIC_RELAXED, __HIP_MEMORY_SCOPE_AGENT);
          if ((a0 >= tgt) & (a1 >= tgt) & (a2 >= tgt) & (a3 >= tgt)) break;
          if (++guard >= (1<<20)) break;
          __builtin_amdgcn_s_sleep(1);
        }
      }
      asm volatile("" ::: "memory");
      __builtin_amdgcn_sched_barrier(0);
      const unsigned* rb = (t&1) ? rb1 : rb0;
      #pragma unroll
      for (int sb=1; sb<4; ++sb){
        const int g2 = (g + sb) & 3;
        const unsigned w = __hip_atomic_load(rb + g2*32 + k32,
                                             __ATOMIC_RELAXED, __HIP_MEMORY_SCOPE_AGENT);
        *reinterpret_cast<unsigned*>(&hbuf[row*264 + g2*64 + j2]) = w;
      }
    }
    __syncthreads();   // B3: hbuf complete for next step
  }
}

// ---- fused attention GEMM + softmax + applied (w*x) + flat bf16 ----
__launch_bounds__(256)
__global__ void attn_applied(const bf16* __restrict__ H2, const bf16* __restrict__ Wap,
                             const float* __restrict__ battn, const int* __restrict__ ids,
                             const float* __restrict__ emb, float* __restrict__ applied,
                             bf16* __restrict__ flat)
{
  __shared__ __align__(16) bf16 albuf[32*264];
  __shared__ float sbuf[32*257];
  const int mt = blockIdx.x, t = blockIdx.y;
  const int b0 = mt*32;
  const int tid = threadIdx.x;
  const int wave = tid >> 6, lane = tid & 63;
  const int l16 = lane & 15, lg = lane >> 4;

  for (int i = tid; i < 1024; i += 256){
    const int r = i >> 5, cc = (i & 31) << 3;
    const int b = b0 + r;
    bf16x8 v;
    if (b < B_) v = *reinterpret_cast<const bf16x8*>(H2 + ((long)b*T_ + t)*256 + cc);
    else { 
      #pragma unroll
      for (int j=0;j<8;j++) v[j] = f2b(0.f);
    }
    *reinterpret_cast<bf16x8*>(&albuf[r*264 + cc]) = v;
  }
  __syncthreads();

  f32x4 acc[2][4];
  #pragma unroll
  for (int ms=0; ms<2; ++ms)
    #pragma unroll
    for (int ns=0; ns<4; ++ns) acc[ms][ns] = f32x4{0.f,0.f,0.f,0.f};

  const bf16* bb = Wap + (long)t*65536 + ((long)(wave*64 + l16) * 32 + lg*8);
  #pragma unroll 2
  for (int q=0; q<8; ++q){
    bf16x8 a0 = *reinterpret_cast<const bf16x8*>(&albuf[l16*264 + q*32 + lg*8]);
    bf16x8 a1 = *reinterpret_cast<const bf16x8*>(&albuf[(16 + l16)*264 + q*32 + lg*8]);
    #pragma unroll
    for (int ns=0; ns<4; ++ns){
      bf16x8 b = *reinterpret_cast<const bf16x8*>(bb + ((long)q*256 + ns*16) * 32);
      acc[0][ns] = __builtin_amdgcn_mfma_f32_16x16x32_bf16(a0, b, acc[0][ns], 0,0,0);
      acc[1][ns] = __builtin_amdgcn_mfma_f32_16x16x32_bf16(a1, b, acc[1][ns], 0,0,0);
    }
  }
  float bv[4];
  #pragma unroll
  for (int ns=0; ns<4; ++ns) bv[ns] = battn[t*256 + wave*64 + ns*16 + l16];
  #pragma unroll
  for (int ms=0; ms<2; ++ms)
    #pragma unroll
    for (int ns=0; ns<4; ++ns)
      #pragma unroll
      for (int r=0; r<4; ++r)
        sbuf[(ms*16 + lg*4 + r)*257 + wave*64 + ns*16 + l16] = acc[ms][ns][r] + bv[ns];
  __syncthreads();

  const int row = tid >> 3, seg = tid & 7;
  const float* srow = &sbuf[row*257 + seg*32];
  float v[32];
  float mx = -1e30f;
  #pragma unroll
  for (int i=0;i<32;++i){ v[i] = srow[i]; mx = fmaxf(mx, v[i]); }
  #pragma unroll
  for (int off=1; off<8; off<<=1) mx = fmaxf(mx, __shfl_xor(mx, off));
  float s = 0.f;
  #pragma unroll
  for (int i=0;i<32;++i){ v[i] = __expf(v[i] - mx); s += v[i]; }
  #pragma unroll
  for (int off=1; off<8; off<<=1) s += __shfl_xor(s, off);
  const float inv = 1.f / s;
  const int b = b0 + row;
  if (b < B_){
    const int id = ids[b*T_ + t];
    const float* ex = emb + (long)id*256 + seg*32;
    float* ap = applied + ((long)b*T_ + t)*256 + seg*32;
    bf16* fp = flat + (long)b*25856 + t*256 + seg*32;
    #pragma unroll
    for (int i=0;i<32;++i){
      const float val = v[i]*inv*ex[i];
      ap[i] = val;
      fp[i] = f2b(val);
    }
  }
}

// ---- W1 GEMM: part[ks][m][n] = flat[m][ks-slice] @ W1p, K-split 8 ----
__launch_bounds__(512)
__global__ void gemm_mlp1(const bf16* __restrict__ A, const bf16* __restrict__ Bp,
                          float* __restrict__ part)
{
  const int m0 = blockIdx.x * 32;
  const int ks = blockIdx.y;
  const int tid = threadIdx.x;
  const int wave = tid >> 6, lane = tid & 63;
  const int l16 = lane & 15, lg = lane >> 4;
  f32x4 acc[2][4];
  #pragma unroll
  for (int ms=0; ms<2; ++ms)
    #pragma unroll
    for (int ns=0; ns<4; ++ns) acc[ms][ns] = f32x4{0.f,0.f,0.f,0.f};

  const bf16* arow0 = A + (long)(m0 + l16)*25856 + lg*8;
  const bf16* arow1 = A + (long)(m0 + 16 + l16)*25856 + lg*8;
  const bf16* bb = Bp + ((long)(wave*64 + l16) * 32 + lg*8);
  #pragma unroll 2
  for (int q = ks*101; q < ks*101 + 101; ++q){
    bf16x8 a0 = *reinterpret_cast<const bf16x8*>(arow0 + (long)q*32);
    bf16x8 a1 = *reinterpret_cast<const bf16x8*>(arow1 + (long)q*32);
    #pragma unroll
    for (int ns=0; ns<4; ++ns){
      bf16x8 b = *reinterpret_cast<const bf16x8*>(bb + ((long)q*512 + ns*16) * 32);
      acc[0][ns] = __builtin_amdgcn_mfma_f32_16x16x32_bf16(a0, b, acc[0][ns], 0,0,0);
      acc[1][ns] = __builtin_amdgcn_mfma_f32_16x16x32_bf16(a1, b, acc[1][ns], 0,0,0);
    }
  }
  #pragma unroll
  for (int ms=0; ms<2; ++ms)
    #pragma unroll
    for (int ns=0; ns<4; ++ns)
      #pragma unroll
      for (int r=0; r<4; ++r)
        part[((long)ks*1024 + m0 + ms*16 + lg*4 + r)*512 + wave*64 + ns*16 + l16] = acc[ms][ns][r];
}

__global__ void reduce_relu(const float* __restrict__ part, const float* __restrict__ b1,
                            float* __restrict__ d1)
{
  const int idx = blockIdx.x*256 + threadIdx.x;   // 524288 exact
  const int n = idx & 511, m = idx >> 9;
  float s = b1[n];
  #pragma unroll
  for (int k=0;k<8;k++) s += part[((long)k*1024 + m)*512 + n];
  d1[idx] = fmaxf(s, 0.f);
}

// ---- MLP layers 2..4 fused, one block per batch row ----
__launch_bounds__(128)
__global__ void mlp_tail(const float* __restrict__ d1, const float* __restrict__ W2T,
                         const float* __restrict__ b2, const float* __restrict__ W3T,
                         const float* __restrict__ b3, const float* __restrict__ Wout,
                         const float* __restrict__ bout, float* __restrict__ tag)
{
  __shared__ float r1[512];
  __shared__ float r2[128];
  __shared__ float r3[64];
  const int b = blockIdx.x;
  const int tid = threadIdx.x;
  for (int i = tid; i < 512; i += 128) r1[i] = d1[(long)b*512 + i];
  __syncthreads();
  float a = b2[tid];
  #pragma unroll 8
  for (int k=0;k<512;++k) a += W2T[k*128 + tid] * r1[k];
  r2[tid] = fmaxf(a, 0.f);
  __syncthreads();
  if (tid < 64){
    float a3 = b3[tid];
    #pragma unroll 8
    for (int k=0;k<128;++k) a3 += W3T[k*64 + tid] * r2[k];
    r3[tid] = fmaxf(a3, 0.f);
  }
  __syncthreads();
  if (tid < 64){
    float p = r3[tid] * Wout[tid];
    #pragma unroll
    for (int off=1; off<64; off<<=1) p += __shfl_xor(p, off);
    if (tid == 0) tag[b] = p + bout[0];
  }
}

extern "C" void kernel_launch(void* const* d_in, const int* in_sizes, int n_in,
                              void* d_out, int out_size, void* d_ws, size_t ws_size,
                              hipStream_t stream)
{
  const int*   ids   = (const int*)  d_in[0];
  const float* emb   = (const float*)d_in[1];
  const float* Wih1  = (const float*)d_in[2];
  const float* Whh1  = (const float*)d_in[3];
  const float* bih1  = (const float*)d_in[4];
  const float* bhh1  = (const float*)d_in[5];
  const float* Wih2  = (const float*)d_in[6];
  const float* Whh2  = (const float*)d_in[7];
  const float* bih2  = (const float*)d_in[8];
  const float* bhh2  = (const float*)d_in[9];
  const float* Wattn = (const float*)d_in[10];
  const float* battn = (const float*)d_in[11];
  const float* W1    = (const float*)d_in[12];
  const float* b1    = (const float*)d_in[13];
  const float* W2    = (const float*)d_in[14];
  const float* b2    = (const float*)d_in[15];
  const float* W3    = (const float*)d_in[16];
  const float* b3    = (const float*)d_in[17];
  const float* Wout  = (const float*)d_in[18];
  const float* bout  = (const float*)d_in[19];
  float* out = (float*)d_out;
  char*  ws  = (char*)d_ws;

  // workspace layout (bytes) — R8 layout
  constexpr size_t OW_IH1 = 0;
  constexpr size_t OW_HH1 = 524288;
  constexpr size_t OW_IH2 = 1048576;
  constexpr size_t OW_HH2 = 1572864;
  constexpr size_t OW_ATT = 2097152;     // 13,238,272
  constexpr size_t OW_W1  = 15335424;    // 26,476,544
  constexpr size_t OW_W2T = 41811968;
  constexpr size_t OW_W3T = 42074112;
  constexpr size_t OXH2   = 42115072;    // h2 output (bf16)
  constexpr size_t OG     = 94248960;    // FLAT + PART region
  constexpr size_t OFLAT  = OG;
  constexpr size_t OPART  = OG + 52953088;
  constexpr size_t OH1    = 302784512;
  constexpr size_t OD1    = 354918400;   // d1 (2MB) — dead during LSTMs:
  constexpr size_t OHX    = OD1;         //   hX: 2 parity x 63 x 8KB
  constexpr size_t OFLG   = OD1 + 1032192; // flags: 2 layers x 4KB
  constexpr size_t NEED   = 357015552;
  if (ws_size < NEED) return;

  bf16*  pIH1 = (bf16*) (ws + OW_IH1);
  bf16*  pHH1 = (bf16*) (ws + OW_HH1);
  bf16*  pIH2 = (bf16*) (ws + OW_IH2);
  bf16*  pHH2 = (bf16*) (ws + OW_HH2);
  bf16*  pATT = (bf16*) (ws + OW_ATT);
  bf16*  pW1  = (bf16*) (ws + OW_W1);
  float* pW2T = (float*)(ws + OW_W2T);
  float* pW3T = (float*)(ws + OW_W3T);
  bf16*  pXH2 = (bf16*) (ws + OXH2);
  bf16*  pFLAT= (bf16*) (ws + OFLAT);
  float* pPART= (float*)(ws + OPART);
  bf16*  pH1  = (bf16*) (ws + OH1);
  float* pD1  = (float*)(ws + OD1);
  unsigned* pHX  = (unsigned*)(ws + OHX);
  unsigned* pFL1 = (unsigned*)(ws + OFLG);
  unsigned* pFL2 = (unsigned*)(ws + OFLG + 4096);

  // zero exchange flags for both LSTM layers (graph-replay safe)
  hipMemsetAsync(ws + OFLG, 0, 8192, stream);
  // flat pad rows [1000,1024) zero
  hipMemsetAsync(ws + OFLAT + (size_t)B_*25856*2, 0, (size_t)24*25856*2, stream);

  // weight packing
  pack_bT<<<dim3(128),        256, 0, stream>>>(Wih1,  pIH1, 1024, 256);
  pack_bT<<<dim3(128),        256, 0, stream>>>(Whh1,  pHH1, 1024, 256);
  pack_bT<<<dim3(128),        256, 0, stream>>>(Wih2,  pIH2, 1024, 256);
  pack_bT<<<dim3(128),        256, 0, stream>>>(Whh2,  pHH2, 1024, 256);
  pack_bT<<<dim3(32, 101),    256, 0, stream>>>(Wattn, pATT, 256,  256);
  pack_bT<<<dim3(6464),       256, 0, stream>>>(W1,    pW1,  512,  25856);
  tr_f32 <<<dim3(256),        256, 0, stream>>>(W2, pW2T, 128, 512);
  tr_f32 <<<dim3(32),         256, 0, stream>>>(W3, pW3T, 64, 128);

  // fused LSTM layers (embedding gathered in-kernel for layer 1)
  lstm_v6<<<dim3(252), 512, 0, stream>>>(nullptr, ids, emb, pIH1, pHH1,
                                         bih1, bhh1, pH1, pHX, pFL1, 1);
  lstm_v6<<<dim3(252), 512, 0, stream>>>(pH1, nullptr, nullptr, pIH2, pHH2,
                                         bih2, bhh2, pXH2, pHX, pFL2, 0);

  // attention + softmax + applied (writes d_out applied region + flat bf16)
  attn_applied<<<dim3(32, 101), 256, 0, stream>>>(pXH2, pATT, battn, ids, emb,
                                                  out + 1000, pFLAT);

  // MLP
  gemm_mlp1  <<<dim3(32, 8), 512, 0, stream>>>(pFLAT, pW1, pPART);
  reduce_relu<<<dim3(2048),  256, 0, stream>>>(pPART, b1, pD1);
  mlp_tail   <<<dim3(1000),  128, 0, stream>>>(pD1, pW2T, b2, pW3T, b3, Wout, bout, out);
}

// Round 16
// 830.754 us; speedup vs baseline: 1.0720x; 1.0720x over previous
//
#include <hip/hip_runtime.h>
#include <hip/hip_bf16.h>

// AttnDecoderRNN on MI355X.
// R8/R9: gates GEMM fused into LSTM, 63 slices x 4 WGs (~280 us/layer).
// R10-R14: further LSTM restructurings all neutral/regressed; R14's
//          in-loop embedding gather put a dependent chain on the
//          critical path (280->325) — reverted to R13's lstm_v5.
// R15: gemm_mlp1 64-row m-tiles (W1p L3 re-reads halve: 845->423MB)
//      with K-split 16 -> grid (16,16)=256 blocks (full GPU, fixing
//      R9's underfill). reduce_relu sums 16 partials. embed_k restored.

#define B_    1000
#define T_    101
#define E_    256
#define H_    256
#define MPAD  101824    // 1591 * 64  >= 1008*T_ = 101808
#define NG    1024      // 4H
#define NSLICE 63

typedef __bf16 bf16;
typedef __bf16 bf16x8 __attribute__((ext_vector_type(8)));
typedef float  f32x4  __attribute__((ext_vector_type(4)));

__device__ __forceinline__ bf16 f2b(float f){
  unsigned u = __builtin_bit_cast(unsigned, f);
  u += 0x7FFFu + ((u >> 16) & 1u);               // RNE
  unsigned short h = (unsigned short)(u >> 16);
  return __builtin_bit_cast(bf16, h);
}
__device__ __forceinline__ unsigned packbf(float a, float b){
  unsigned ua = __builtin_bit_cast(unsigned, a);
  ua += 0x7FFFu + ((ua >> 16) & 1u);
  unsigned ub = __builtin_bit_cast(unsigned, b);
  ub += 0x7FFFu + ((ub >> 16) & 1u);
  return (ua >> 16) | (ub & 0xffff0000u);
}
__device__ __forceinline__ float sigm(float x){ return 1.f/(1.f + __expf(-x)); }
__device__ __forceinline__ float tanh_(float x){ return 2.f/(1.f + __expf(-2.f*x)) - 1.f; }

// ---- pack W[N][K] f32 -> Bp[K/32][N][32] bf16 (MFMA B-fragment order) ----
__global__ void pack_bT(const float* __restrict__ src, bf16* __restrict__ dst,
                        int N, int K)
{
  const long batch = blockIdx.y;
  src += batch * (long)N * K;
  dst += batch * (long)(K/32) * N * 32;
  const int tid = blockIdx.x * blockDim.x + threadIdx.x;
  const int total = (K/32) * N * 4;
  if (tid >= total) return;
  const int kkc = tid & 3;
  const int rem = tid >> 2;
  const int n = rem % N;
  const int q = rem / N;
  const float* s = src + (long)n*K + q*32 + kkc*8;
  bf16x8 v;
  #pragma unroll
  for (int e=0;e<8;e++) v[e] = f2b(s[e]);
  *reinterpret_cast<bf16x8*>(dst + ((long)q*N + n)*32 + kkc*8) = v;
}

// ---- f32 transpose: dst[k][j] = src[j][k], src is [N][K] ----
__global__ void tr_f32(const float* __restrict__ src, float* __restrict__ dst,
                       int N, int K)
{
  const int id = blockIdx.x * blockDim.x + threadIdx.x;
  if (id >= N*K) return;
  const int k = id / N, j = id % N;
  dst[(long)k*N + j] = src[(long)j*K + k];
}

__global__ void bias_sum(const float* __restrict__ a, const float* __restrict__ b,
                         float* __restrict__ o, int n)
{
  const int i = blockIdx.x * blockDim.x + threadIdx.x;
  if (i < n) o[i] = a[i] + b[i];
}

// ---- embedding gather -> x bf16 [MPAD][256], zeros for pad rows ----
__global__ void embed_k(const int* __restrict__ ids, const float* __restrict__ emb,
                        bf16* __restrict__ x)
{
  const int tid = blockIdx.x * blockDim.x + threadIdx.x;   // MPAD*32 exact
  const int m = tid >> 5;
  const int c = (tid & 31) << 3;
  bf16x8 v;
  if (m < B_*T_) {
    const int id = ids[m];
    const float* e = emb + (long)id*E_ + c;
    #pragma unroll
    for (int j=0;j<8;j++) v[j] = f2b(e[j]);
  } else {
    #pragma unroll
    for (int j=0;j<8;j++) v[j] = f2b(0.f);
  }
  *reinterpret_cast<bf16x8*>(x + (long)m*256 + c) = v;
}

// ---- fused LSTM: 63 slices x 4 WGs; per-WG flag words (R13 best) ----
#define MF(a,b,c) __builtin_amdgcn_mfma_f32_16x16x32_bf16((a),(b),(c),0,0,0)
#define LDW(q_,off_)  (*reinterpret_cast<const bf16x8*>(bbW + ((long)(q_)*NG + (off_))*32))
#define LDX8(q_,off_) (*reinterpret_cast<const bf16x8*>(bbX + ((long)(q_)*NG + (off_))*32))

#define XK_ALL() { \
  bf16x8 xA0 = LDX8(0,0), xA1 = LDX8(0,16), xB0, xB1; \
  _Pragma("unroll") \
  for (int h2x=0; h2x<4; ++h2x){ \
    const int q0x = 2*h2x; \
    xB0 = LDX8(q0x+1,0); xB1 = LDX8(q0x+1,16); \
    { bf16x8 ax = *reinterpret_cast<const bf16x8*>(&xbuf[l16*264 + q0x*32 + lg*8]); \
      acc0 = MF(ax,xA0,acc0); acc1 = MF(ax,xA1,acc1); } \
    if (q0x+2 < 8){ xA0 = LDX8(q0x+2,0); xA1 = LDX8(q0x+2,16); } \
    { bf16x8 ax = *reinterpret_cast<const bf16x8*>(&xbuf[l16*264 + (q0x+1)*32 + lg*8]); \
      acc0 = MF(ax,xB0,acc0); acc1 = MF(ax,xB1,acc1); } \
  } }

__launch_bounds__(512, 1)
__global__ void lstm_v5(const bf16* __restrict__ X, const bf16* __restrict__ Wihp,
                        const bf16* __restrict__ Whhp, const float* __restrict__ bias,
                        bf16* __restrict__ Hout, unsigned* __restrict__ hX,
                        unsigned* __restrict__ flags)
{
  __shared__ __align__(16) bf16 hbuf[16*264];   // h_{t-1}/h_t (16 x 256, padded)
  __shared__ __align__(16) bf16 xbuf[16*264];   // x_t / x_{t+1}
  __shared__ float gstage[256*17];               // gate partials [local col][row]
  const int bid = blockIdx.x;
  const int s = bid >> 2, g = bid & 3;
  const int b0 = s * 16;
  const int tid = threadIdx.x;
  const int wave = tid >> 6, lane = tid & 63;
  const int l16 = lane & 15, lg = lane >> 4;
  const int qd  = wave >> 1;               // gate quadrant of this wave
  const int h32 = (wave & 1) * 32;         // 32-col half within the 64

  const bf16* bbW = Whhp + ((long)(qd*256 + g*64 + h32 + l16) * 32 + lg*8);
  const bf16* bbX = Wihp + ((long)(qd*256 + g*64 + h32 + l16) * 32 + lg*8);

  const int row = tid >> 5;            // 0..15
  const int k32 = tid & 31;
  const int j2  = k32 * 2;             // [0,64)
  float c0 = 0.f, c1 = 0.f;

  const long grow = (long)(b0 + row) * T_;
  const bf16* xp  = X    + grow*256 + k32*8;   // 16B x-slice per thread
  bf16*       hop = Hout + grow*256 + g*64 + j2;

  const float bvi0 = bias[      g*64 + j2    ];
  const float bvi1 = bias[      g*64 + j2 + 1];
  const float bvf0 = bias[256 + g*64 + j2    ];
  const float bvf1 = bias[256 + g*64 + j2 + 1];
  const float bvg0 = bias[512 + g*64 + j2    ];
  const float bvg1 = bias[512 + g*64 + j2 + 1];
  const float bvo0 = bias[768 + g*64 + j2    ];
  const float bvo1 = bias[768 + g*64 + j2 + 1];

  unsigned* flagw = flags + s*16;       // 4 words per slice, 64B line
  unsigned* hx0 = hX + (size_t)s*2048 + row*128 + g*32 + k32;
  unsigned* hx1 = hx0 + (size_t)NSLICE*2048;
  const unsigned* rb0 = hX + (size_t)s*2048 + row*128;
  const unsigned* rb1 = rb0 + (size_t)NSLICE*2048;

  const int qo0 = 2*g, qo1 = 2*g + 1;    // Whh K-chunks covering own h-cols

  for (int i = tid; i < 16*264; i += 512) hbuf[i] = f2b(0.f);
  *reinterpret_cast<bf16x8*>(&xbuf[row*264 + k32*8]) =
      *reinterpret_cast<const bf16x8*>(xp);          // x_0
  __syncthreads();

  bf16x8 f0[6], f1[6];                   // remK weights (wait-window refresh)
  #pragma unroll
  for (int i=0;i<6;++i){
    const int qn = (qo0 + 2 + i) & 7;
    f0[i] = LDW(qn, 0);
    f1[i] = LDW(qn, 16);
  }

  // prologue: acc = x-K(x_0); h_{-1}=0 so h-K contributes nothing
  f32x4 acc0 = {0.f,0.f,0.f,0.f}, acc1 = {0.f,0.f,0.f,0.f};
  XK_ALL();

  for (int t = 0; t < T_; ++t){
    // x_{t+1} prefetch (HBM; consumed at LDS write after elementwise)
    const bf16x8 xreg = *reinterpret_cast<const bf16x8*>(xp + (long)(t+1)*256);

    // --- remK: 6 Whh chunks over sibling h-cols ---
    #pragma unroll
    for (int i = 0; i < 6; ++i){
      const int qi = (qo0 + 2 + i) & 7;
      bf16x8 a = *reinterpret_cast<const bf16x8*>(&hbuf[l16*264 + qi*32 + lg*8]);
      acc0 = MF(a, f0[i], acc0);
      acc1 = MF(a, f1[i], acc1);
    }
    // dump gate partials, transposed [local col][17]
    {
      const int jj = wave*32 + l16;
      float* gc0 = &gstage[jj*17 + lg*4];
      gc0[0]=acc0[0]; gc0[1]=acc0[1]; gc0[2]=acc0[2]; gc0[3]=acc0[3];
      float* gc1 = &gstage[(jj+16)*17 + lg*4];
      gc1[0]=acc1[0]; gc1[1]=acc1[1]; gc1[2]=acc1[2]; gc1[3]=acc1[3];
    }
    __syncthreads();   // B1: gstage visible; hbuf/xbuf reads done

    // --- elementwise: 2 h-cols per thread ---
    const float i0 = sigm (bvi0 + gstage[(j2      )*17 + row]);
    const float i1 = sigm (bvi1 + gstage[(j2 +   1)*17 + row]);
    const float f0e= sigm (bvf0 + gstage[(j2 +  64)*17 + row]);
    const float f1e= sigm (bvf1 + gstage[(j2 +  65)*17 + row]);
    const float g0e= tanh_(bvg0 + gstage[(j2 + 128)*17 + row]);
    const float g1e= tanh_(bvg1 + gstage[(j2 + 129)*17 + row]);
    const float o0 = sigm (bvo0 + gstage[(j2 + 192)*17 + row]);
    const float o1 = sigm (bvo1 + gstage[(j2 + 193)*17 + row]);
    c0 = f0e*c0 + i0*g0e;
    c1 = f1e*c1 + i1*g1e;
    const unsigned hw = packbf(o0*tanh_(c0), o1*tanh_(c1));

    // own h -> hbuf; x_{t+1} -> xbuf; publish h -> LLC (pre-flag drain)
    *reinterpret_cast<unsigned*>(&hbuf[row*264 + g*64 + j2]) = hw;
    *reinterpret_cast<bf16x8*>(&xbuf[row*264 + k32*8]) = xreg;
    __hip_atomic_store((t&1) ? hx1 : hx0, hw, __ATOMIC_RELAXED, __HIP_MEMORY_SCOPE_AGENT);

    __syncthreads();   // B2: drains hX publish
    if (tid == 0)
      __hip_atomic_store(flagw + g, (unsigned)(t+1),
                         __ATOMIC_RELAXED, __HIP_MEMORY_SCOPE_AGENT);

    // Hout store off the pre-flag drain path
    *reinterpret_cast<unsigned*>(hop + (long)t*256) = hw;

    // --- wait window: own-K(h_t) + x-K(x_{t+1}) + remK weight refresh ---
    {
      bf16x8 o00 = LDW(qo0, 0), o01 = LDW(qo0, 16);
      bf16x8 o10 = LDW(qo1, 0), o11 = LDW(qo1, 16);
      acc0 = f32x4{0.f,0.f,0.f,0.f};
      acc1 = f32x4{0.f,0.f,0.f,0.f};
      bf16x8 a0 = *reinterpret_cast<const bf16x8*>(&hbuf[l16*264 + qo0*32 + lg*8]);
      acc0 = MF(a0, o00, acc0); acc1 = MF(a0, o01, acc1);
      bf16x8 a1 = *reinterpret_cast<const bf16x8*>(&hbuf[l16*264 + qo1*32 + lg*8]);
      acc0 = MF(a1, o10, acc0); acc1 = MF(a1, o11, acc1);
      XK_ALL();
      #pragma unroll
      for (int i=0;i<6;++i){
        const int qn = (qo0 + 2 + i) & 7;
        f0[i] = LDW(qn, 0);
        f1[i] = LDW(qn, 16);
      }
    }

    // --- wait all 4 WGs (poll 4 per-WG words), pull siblings' h-blocks ---
    {
      const unsigned tgt = (unsigned)(t+1);
      if (lane == 0){
        int guard = 0;
        for (;;){
          const unsigned a0 = __hip_atomic_load(flagw+0, __ATOMIC_RELAXED, __HIP_MEMORY_SCOPE_AGENT);
          const unsigned a1 = __hip_atomic_load(flagw+1, __ATOMIC_RELAXED, __HIP_MEMORY_SCOPE_AGENT);
          const unsigned a2 = __hip_atomic_load(flagw+2, __ATOMIC_RELAXED, __HIP_MEMORY_SCOPE_AGENT);
          const unsigned a3 = __hip_atomic_load(flagw+3, __ATOMIC_RELAXED, __HIP_MEMORY_SCOPE_AGENT);
          if ((a0 >= tgt) & (a1 >= tgt) & (a2 >= tgt) & (a3 >= tgt)) break;
          if (++guard >= (1<<20)) break;
          __builtin_amdgcn_s_sleep(1);
        }
      }
      asm volatile("" ::: "memory");
      __builtin_amdgcn_sched_barrier(0);
      const unsigned* rb = (t&1) ? rb1 : rb0;
      #pragma unroll
      for (int sb=1; sb<4; ++sb){
        const int g2 = (g + sb) & 3;
        const unsigned w = __hip_atomic_load(rb + g2*32 + k32,
                                             __ATOMIC_RELAXED, __HIP_MEMORY_SCOPE_AGENT);
        *reinterpret_cast<unsigned*>(&hbuf[row*264 + g2*64 + j2]) = w;
      }
    }
    __syncthreads();   // B3: hbuf complete for next step
  }
}

// ---- fused attention GEMM + softmax + applied (w*x) + flat bf16 ----
__launch_bounds__(256)
__global__ void attn_applied(const bf16* __restrict__ H2, const bf16* __restrict__ Wap,
                             const float* __restrict__ battn, const int* __restrict__ ids,
                             const float* __restrict__ emb, float* __restrict__ applied,
                             bf16* __restrict__ flat)
{
  __shared__ __align__(16) bf16 albuf[32*264];
  __shared__ float sbuf[32*257];
  const int mt = blockIdx.x, t = blockIdx.y;
  const int b0 = mt*32;
  const int tid = threadIdx.x;
  const int wave = tid >> 6, lane = tid & 63;
  const int l16 = lane & 15, lg = lane >> 4;

  for (int i = tid; i < 1024; i += 256){
    const int r = i >> 5, cc = (i & 31) << 3;
    const int b = b0 + r;
    bf16x8 v;
    if (b < B_) v = *reinterpret_cast<const bf16x8*>(H2 + ((long)b*T_ + t)*256 + cc);
    else { 
      #pragma unroll
      for (int j=0;j<8;j++) v[j] = f2b(0.f);
    }
    *reinterpret_cast<bf16x8*>(&albuf[r*264 + cc]) = v;
  }
  __syncthreads();

  f32x4 acc[2][4];
  #pragma unroll
  for (int ms=0; ms<2; ++ms)
    #pragma unroll
    for (int ns=0; ns<4; ++ns) acc[ms][ns] = f32x4{0.f,0.f,0.f,0.f};

  const bf16* bb = Wap + (long)t*65536 + ((long)(wave*64 + l16) * 32 + lg*8);
  #pragma unroll 2
  for (int q=0; q<8; ++q){
    bf16x8 a0 = *reinterpret_cast<const bf16x8*>(&albuf[l16*264 + q*32 + lg*8]);
    bf16x8 a1 = *reinterpret_cast<const bf16x8*>(&albuf[(16 + l16)*264 + q*32 + lg*8]);
    #pragma unroll
    for (int ns=0; ns<4; ++ns){
      bf16x8 b = *reinterpret_cast<const bf16x8*>(bb + ((long)q*256 + ns*16) * 32);
      acc[0][ns] = __builtin_amdgcn_mfma_f32_16x16x32_bf16(a0, b, acc[0][ns], 0,0,0);
      acc[1][ns] = __builtin_amdgcn_mfma_f32_16x16x32_bf16(a1, b, acc[1][ns], 0,0,0);
    }
  }
  float bv[4];
  #pragma unroll
  for (int ns=0; ns<4; ++ns) bv[ns] = battn[t*256 + wave*64 + ns*16 + l16];
  #pragma unroll
  for (int ms=0; ms<2; ++ms)
    #pragma unroll
    for (int ns=0; ns<4; ++ns)
      #pragma unroll
      for (int r=0; r<4; ++r)
        sbuf[(ms*16 + lg*4 + r)*257 + wave*64 + ns*16 + l16] = acc[ms][ns][r] + bv[ns];
  __syncthreads();

  const int row = tid >> 3, seg = tid & 7;
  const float* srow = &sbuf[row*257 + seg*32];
  float v[32];
  float mx = -1e30f;
  #pragma unroll
  for (int i=0;i<32;++i){ v[i] = srow[i]; mx = fmaxf(mx, v[i]); }
  #pragma unroll
  for (int off=1; off<8; off<<=1) mx = fmaxf(mx, __shfl_xor(mx, off));
  float s = 0.f;
  #pragma unroll
  for (int i=0;i<32;++i){ v[i] = __expf(v[i] - mx); s += v[i]; }
  #pragma unroll
  for (int off=1; off<8; off<<=1) s += __shfl_xor(s, off);
  const float inv = 1.f / s;
  const int b = b0 + row;
  if (b < B_){
    const int id = ids[b*T_ + t];
    const float* ex = emb + (long)id*256 + seg*32;
    float* ap = applied + ((long)b*T_ + t)*256 + seg*32;
    bf16* fp = flat + (long)b*25856 + t*256 + seg*32;
    #pragma unroll
    for (int i=0;i<32;++i){
      const float val = v[i]*inv*ex[i];
      ap[i] = val;
      fp[i] = f2b(val);
    }
  }
}

// ---- W1 GEMM: 64-row m-tiles, K-split 16 (grid 16x16 = 256 blocks) ----
// chunk split: ks<8 -> 51 q-chunks (start ks*51), else 50 (start 408+(ks-8)*50)
__launch_bounds__(512, 2)
__global__ void gemm_mlp1(const bf16* __restrict__ A, const bf16* __restrict__ Bp,
                          float* __restrict__ part)
{
  const int m0 = blockIdx.x * 64;
  const int ks = blockIdx.y;
  const int q0 = (ks < 8) ? ks*51 : 408 + (ks-8)*50;
  const int qn = (ks < 8) ? 51 : 50;
  const int tid = threadIdx.x;
  const int wave = tid >> 6, lane = tid & 63;
  const int l16 = lane & 15, lg = lane >> 4;
  f32x4 acc[4][4];
  #pragma unroll
  for (int ms=0; ms<4; ++ms)
    #pragma unroll
    for (int ns=0; ns<4; ++ns) acc[ms][ns] = f32x4{0.f,0.f,0.f,0.f};

  const bf16* arow0 = A + (long)(m0      + l16)*25856 + lg*8;
  const bf16* arow1 = A + (long)(m0 + 16 + l16)*25856 + lg*8;
  const bf16* arow2 = A + (long)(m0 + 32 + l16)*25856 + lg*8;
  const bf16* arow3 = A + (long)(m0 + 48 + l16)*25856 + lg*8;
  const bf16* bb = Bp + ((long)(wave*64 + l16) * 32 + lg*8);
  #pragma unroll 2
  for (int qq = 0; qq < qn; ++qq){
    const int q = q0 + qq;
    bf16x8 a0 = *reinterpret_cast<const bf16x8*>(arow0 + (long)q*32);
    bf16x8 a1 = *reinterpret_cast<const bf16x8*>(arow1 + (long)q*32);
    bf16x8 a2 = *reinterpret_cast<const bf16x8*>(arow2 + (long)q*32);
    bf16x8 a3 = *reinterpret_cast<const bf16x8*>(arow3 + (long)q*32);
    #pragma unroll
    for (int ns=0; ns<4; ++ns){
      bf16x8 b = *reinterpret_cast<const bf16x8*>(bb + ((long)q*512 + ns*16) * 32);
      acc[0][ns] = __builtin_amdgcn_mfma_f32_16x16x32_bf16(a0, b, acc[0][ns], 0,0,0);
      acc[1][ns] = __builtin_amdgcn_mfma_f32_16x16x32_bf16(a1, b, acc[1][ns], 0,0,0);
      acc[2][ns] = __builtin_amdgcn_mfma_f32_16x16x32_bf16(a2, b, acc[2][ns], 0,0,0);
      acc[3][ns] = __builtin_amdgcn_mfma_f32_16x16x32_bf16(a3, b, acc[3][ns], 0,0,0);
    }
  }
  #pragma unroll
  for (int ms=0; ms<4; ++ms)
    #pragma unroll
    for (int ns=0; ns<4; ++ns)
      #pragma unroll
      for (int r=0; r<4; ++r)
        part[((long)ks*1024 + m0 + ms*16 + lg*4 + r)*512 + wave*64 + ns*16 + l16] = acc[ms][ns][r];
}

__global__ void reduce_relu(const float* __restrict__ part, const float* __restrict__ b1,
                            float* __restrict__ d1)
{
  const int idx = blockIdx.x*256 + threadIdx.x;   // 524288 exact
  const int n = idx & 511, m = idx >> 9;
  float s = b1[n];
  #pragma unroll
  for (int k=0;k<16;k++) s += part[((long)k*1024 + m)*512 + n];
  d1[idx] = fmaxf(s, 0.f);
}

// ---- MLP layers 2..4 fused, one block per batch row ----
__launch_bounds__(128)
__global__ void mlp_tail(const float* __restrict__ d1, const float* __restrict__ W2T,
                         const float* __restrict__ b2, const float* __restrict__ W3T,
                         const float* __restrict__ b3, const float* __restrict__ Wout,
                         const float* __restrict__ bout, float* __restrict__ tag)
{
  __shared__ float r1[512];
  __shared__ float r2[128];
  __shared__ float r3[64];
  const int b = blockIdx.x;
  const int tid = threadIdx.x;
  for (int i = tid; i < 512; i += 128) r1[i] = d1[(long)b*512 + i];
  __syncthreads();
  float a = b2[tid];
  #pragma unroll 8
  for (int k=0;k<512;++k) a += W2T[k*128 + tid] * r1[k];
  r2[tid] = fmaxf(a, 0.f);
  __syncthreads();
  if (tid < 64){
    float a3 = b3[tid];
    #pragma unroll 8
    for (int k=0;k<128;++k) a3 += W3T[k*64 + tid] * r2[k];
    r3[tid] = fmaxf(a3, 0.f);
  }
  __syncthreads();
  if (tid < 64){
    float p = r3[tid] * Wout[tid];
    #pragma unroll
    for (int off=1; off<64; off<<=1) p += __shfl_xor(p, off);
    if (tid == 0) tag[b] = p + bout[0];
  }
}

extern "C" void kernel_launch(void* const* d_in, const int* in_sizes, int n_in,
                              void* d_out, int out_size, void* d_ws, size_t ws_size,
                              hipStream_t stream)
{
  const int*   ids   = (const int*)  d_in[0];
  const float* emb   = (const float*)d_in[1];
  const float* Wih1  = (const float*)d_in[2];
  const float* Whh1  = (const float*)d_in[3];
  const float* bih1  = (const float*)d_in[4];
  const float* bhh1  = (const float*)d_in[5];
  const float* Wih2  = (const float*)d_in[6];
  const float* Whh2  = (const float*)d_in[7];
  const float* bih2  = (const float*)d_in[8];
  const float* bhh2  = (const float*)d_in[9];
  const float* Wattn = (const float*)d_in[10];
  const float* battn = (const float*)d_in[11];
  const float* W1    = (const float*)d_in[12];
  const float* b1    = (const float*)d_in[13];
  const float* W2    = (const float*)d_in[14];
  const float* b2    = (const float*)d_in[15];
  const float* W3    = (const float*)d_in[16];
  const float* b3    = (const float*)d_in[17];
  const float* Wout  = (const float*)d_in[18];
  const float* bout  = (const float*)d_in[19];
  float* out = (float*)d_out;
  char*  ws  = (char*)d_ws;

  // workspace layout (bytes) — R8 layout (PART now 16x1024x512 f32 = 33.5MB)
  constexpr size_t OW_IH1 = 0;
  constexpr size_t OW_HH1 = 524288;
  constexpr size_t OW_IH2 = 1048576;
  constexpr size_t OW_HH2 = 1572864;
  constexpr size_t OW_ATT = 2097152;     // 13,238,272
  constexpr size_t OW_W1  = 15335424;    // 26,476,544
  constexpr size_t OW_W2T = 41811968;
  constexpr size_t OW_W3T = 42074112;
  constexpr size_t OB1    = 42106880;
  constexpr size_t OB2    = 42110976;
  constexpr size_t OXH2   = 42115072;    // x bf16, later h2 (alias)
  constexpr size_t OG     = 94248960;    // FLAT + PART region
  constexpr size_t OFLAT  = OG;
  constexpr size_t OPART  = OG + 52953088;   // 33.5MB fits (region is 208MB)
  constexpr size_t OH1    = 302784512;
  constexpr size_t OD1    = 354918400;   // d1 (2MB) — dead during LSTMs:
  constexpr size_t OHX    = OD1;         //   hX: 2 parity x 63 x 8KB
  constexpr size_t OFLG   = OD1 + 1032192; // flags: 2 layers x 4KB
  constexpr size_t NEED   = 357015552;
  if (ws_size < NEED) return;

  bf16*  pIH1 = (bf16*) (ws + OW_IH1);
  bf16*  pHH1 = (bf16*) (ws + OW_HH1);
  bf16*  pIH2 = (bf16*) (ws + OW_IH2);
  bf16*  pHH2 = (bf16*) (ws + OW_HH2);
  bf16*  pATT = (bf16*) (ws + OW_ATT);
  bf16*  pW1  = (bf16*) (ws + OW_W1);
  float* pW2T = (float*)(ws + OW_W2T);
  float* pW3T = (float*)(ws + OW_W3T);
  float* pB1  = (float*)(ws + OB1);
  float* pB2  = (float*)(ws + OB2);
  bf16*  pXH2 = (bf16*) (ws + OXH2);
  bf16*  pFLAT= (bf16*) (ws + OFLAT);
  float* pPART= (float*)(ws + OPART);
  bf16*  pH1  = (bf16*) (ws + OH1);
  float* pD1  = (float*)(ws + OD1);
  unsigned* pHX  = (unsigned*)(ws + OHX);
  unsigned* pFL1 = (unsigned*)(ws + OFLG);
  unsigned* pFL2 = (unsigned*)(ws + OFLG + 4096);

  // zero exchange flags for both LSTM layers (graph-replay safe)
  hipMemsetAsync(ws + OFLG, 0, 8192, stream);
  // flat pad rows [1000,1024) zero
  hipMemsetAsync(ws + OFLAT + (size_t)B_*25856*2, 0, (size_t)24*25856*2, stream);

  // weight packing
  pack_bT<<<dim3(128),        256, 0, stream>>>(Wih1,  pIH1, 1024, 256);
  pack_bT<<<dim3(128),        256, 0, stream>>>(Whh1,  pHH1, 1024, 256);
  pack_bT<<<dim3(128),        256, 0, stream>>>(Wih2,  pIH2, 1024, 256);
  pack_bT<<<dim3(128),        256, 0, stream>>>(Whh2,  pHH2, 1024, 256);
  pack_bT<<<dim3(32, 101),    256, 0, stream>>>(Wattn, pATT, 256,  256);
  pack_bT<<<dim3(6464),       256, 0, stream>>>(W1,    pW1,  512,  25856);
  tr_f32 <<<dim3(256),        256, 0, stream>>>(W2, pW2T, 128, 512);
  tr_f32 <<<dim3(32),         256, 0, stream>>>(W3, pW3T, 64, 128);
  bias_sum<<<dim3(4),         256, 0, stream>>>(bih1, bhh1, pB1, 1024);
  bias_sum<<<dim3(4),         256, 0, stream>>>(bih2, bhh2, pB2, 1024);

  // embed -> x bf16
  embed_k<<<dim3(12728), 256, 0, stream>>>(ids, emb, pXH2);

  // fused LSTM layers (gates GEMM folded in)
  lstm_v5<<<dim3(252), 512, 0, stream>>>(pXH2, pIH1, pHH1, pB1, pH1,  pHX, pFL1);
  lstm_v5<<<dim3(252), 512, 0, stream>>>(pH1,  pIH2, pHH2, pB2, pXH2, pHX, pFL2);

  // attention + softmax + applied (writes d_out applied region + flat bf16)
  attn_applied<<<dim3(32, 101), 256, 0, stream>>>(pXH2, pATT, battn, ids, emb,
                                                  out + 1000, pFLAT);

  // MLP
  gemm_mlp1  <<<dim3(16, 16), 512, 0, stream>>>(pFLAT, pW1, pPART);
  reduce_relu<<<dim3(2048),   256, 0, stream>>>(pPART, b1, pD1);
  mlp_tail   <<<dim3(1000),   128, 0, stream>>>(pD1, pW2T, b2, pW3T, b3, Wout, bout, out);
}